// Round 6
// baseline (526.061 us; speedup 1.0000x reference)
//
#include <hip/hip_runtime.h>
#include <hip/hip_cooperative_groups.h>

namespace cg = cooperative_groups;

// QuantumMotivicTile — B=4, S=2048, H=16, hd=64, D=1024, fp32 I/O.
// final = softmax(q k^T / 8) @ v'' + ecv   (all weight algebra pre-folded)
//   Aq = QS·Wq·Wi (log2-domain scores, exp2 softmax), Ak = Wk·Wi,
//   Av = M·Wv·Wi, M = Wmi·Wm·Wci·Wc (rank 4), ecv = M·(Wv·bi+bv) + cvec.
// R6: (1) fold kernel on MFMA; (2) kv+attn merged into ONE cooperative kernel
// with grid.sync (fallback: two launches); (3) bound-based softmax — no online
// max/rescale: M_row = ||q'||1 * max|k| * 1.02, exp2(s-M) safe in fp32.

#define SEQ 2048
#define DM  1024
#define QS  0.180336880111120429f  // 0.125 * log2(e)

typedef short bf16x8 __attribute__((ext_vector_type(8)));
typedef unsigned short u16x8 __attribute__((ext_vector_type(8)));
typedef float f32x16 __attribute__((ext_vector_type(16)));

#define MFMA32 __builtin_amdgcn_mfma_f32_32x32x16_bf16

#if defined(__has_builtin)
#if __has_builtin(__builtin_amdgcn_exp2f)
#define EXP2(x) __builtin_amdgcn_exp2f(x)
#endif
#endif
#ifndef EXP2
#define EXP2(x) exp2f(x)
#endif

// ws layout:
//   float [0..63] bq' (×QS), [64..127] ecv, [128] max|k| (float bits, atomicMax as int)
//   ushort wsu = (ushort*)(ws + 144):
//     [0..4095] Aq, [4096..8191] Ak, [8192..12287] Av   (row-major [dout][din])
//     [12288..) Kg[bh][key][dout]; [+8388608..) Vtg[bh][dout][key]
#define FOLD_F 144
#define KG_OFF 12288
#define VG_OFF (12288 + 8388608)

__device__ __forceinline__ unsigned short f2bf(float f) {
    unsigned int v = __float_as_uint(f);
    unsigned int r = v + 0x7FFFu + ((v >> 16) & 1u);
    return (unsigned short)(r >> 16);
}
__device__ __forceinline__ unsigned int pk2r(float a, float b) {  // round
    return __builtin_amdgcn_perm(__float_as_uint(b) + 0x8000u,
                                 __float_as_uint(a) + 0x8000u, 0x07060302u);
}
__device__ __forceinline__ unsigned int pk2t(float a, float b) {  // truncate
    return __builtin_amdgcn_perm(__float_as_uint(b), __float_as_uint(a), 0x07060302u);
}
__device__ __forceinline__ f32x16 z16() {
    f32x16 v;
    #pragma unroll
    for (int i = 0; i < 16; i++) v[i] = 0.f;
    return v;
}

// ---------------- weight folding (1 block, 256 thr, MFMA) ----------------
__global__ __launch_bounds__(256)
void qmt_fold(const float* __restrict__ Wi,  const float* __restrict__ bi,
              const float* __restrict__ Wq,  const float* __restrict__ bq,
              const float* __restrict__ Wk,  const float* __restrict__ bk,
              const float* __restrict__ Wv,  const float* __restrict__ bv,
              const float* __restrict__ Wc,  const float* __restrict__ bc,
              const float* __restrict__ Wci, const float* __restrict__ bci,
              const float* __restrict__ Wm,  const float* __restrict__ bm,
              const float* __restrict__ Wmi, const float* __restrict__ bmi,
              float* __restrict__ ws) {
    const int tid = threadIdx.x;
    const int o = tid & 63;
    const int w = tid >> 6;
    const int lane = tid & 63;
    const int ln = lane & 31;
    const int h = lane >> 5;

    __shared__ float Wi_s[64 * 68], Wq_s[64 * 68], Wk_s[64 * 68], Wv_s[64 * 68];
    __shared__ float M_s[64 * 68];
    __shared__ __align__(16) unsigned short Wvit[64 * 72];  // Wvi^T [din][dout] bf16
    __shared__ float Wc_s[512], Wci_s[512], Wm_s[256], Wmi_s[256];
    __shared__ float bi_s[64], bvi_s[64], c1[64], c2[4], U1[32], U2[256];

    unsigned short* wsu = (unsigned short*)(ws + FOLD_F);

    for (int i4 = tid; i4 < 1024; i4 += 256) {
        int r = i4 >> 4, c = (i4 & 15) * 4;
        *(float4*)&Wi_s[r * 68 + c] = *(const float4*)(Wi + i4 * 4);
        *(float4*)&Wq_s[r * 68 + c] = *(const float4*)(Wq + i4 * 4);
        *(float4*)&Wk_s[r * 68 + c] = *(const float4*)(Wk + i4 * 4);
        *(float4*)&Wv_s[r * 68 + c] = *(const float4*)(Wv + i4 * 4);
    }
    if (tid < 128) {
        *(float4*)&Wc_s[tid * 4]  = *(const float4*)(Wc + tid * 4);
        *(float4*)&Wci_s[tid * 4] = *(const float4*)(Wci + tid * 4);
    } else if (tid < 192) {
        int t = tid - 128;
        *(float4*)&Wm_s[t * 4]  = *(const float4*)(Wm + t * 4);
        *(float4*)&Wmi_s[t * 4] = *(const float4*)(Wmi + t * 4);
    }
    if (tid < 64) bi_s[tid] = bi[tid];
    if (tid == 0) ((int*)ws)[128] = 0;  // max|k| accumulator
    __syncthreads();

    const int mt = (w >> 1) & 1;  // output row tile
    const int nt = w & 1;         // output col tile
    // B-frags of Wi^T for this wave's n-tile (built once, reused by 3 products)
    bf16x8 wib[4];
    #pragma unroll
    for (int c = 0; c < 4; c++) {
        union { bf16x8 v; unsigned int u[4]; } t;
        #pragma unroll
        for (int j = 0; j < 4; j++) {
            float a = Wi_s[(c * 16 + h * 8 + 2 * j) * 68 + nt * 32 + ln];
            float b = Wi_s[(c * 16 + h * 8 + 2 * j + 1) * 68 + nt * 32 + ln];
            t.u[j] = pk2r(a, b);
        }
        wib[c] = t.v;
    }
    // products 0:Aq(×QS) 1:Ak 2:Wvi(→ transposed LDS)
    #pragma unroll
    for (int p = 0; p < 3; p++) {
        const float* src = (p == 0) ? Wq_s : (p == 1) ? Wk_s : Wv_s;
        f32x16 d = z16();
        #pragma unroll
        for (int c = 0; c < 4; c++) {
            const float* ap = src + (mt * 32 + ln) * 68 + c * 16 + h * 8;
            float4 a0 = *(const float4*)ap;
            float4 a1 = *(const float4*)(ap + 4);
            union { bf16x8 v; unsigned int u[4]; } t;
            t.u[0] = pk2r(a0.x, a0.y); t.u[1] = pk2r(a0.z, a0.w);
            t.u[2] = pk2r(a1.x, a1.y); t.u[3] = pk2r(a1.z, a1.w);
            d = MFMA32(t.v, wib[c], d, 0, 0, 0);
        }
        if (p == 0) {
            #pragma unroll
            for (int g = 0; g < 4; g++)
                #pragma unroll
                for (int i = 0; i < 4; i++)
                    wsu[(mt * 32 + 8 * g + 4 * h + i) * 64 + nt * 32 + ln] = f2bf(d[4 * g + i] * QS);
        } else if (p == 1) {
            #pragma unroll
            for (int g = 0; g < 4; g++)
                #pragma unroll
                for (int i = 0; i < 4; i++)
                    wsu[4096 + (mt * 32 + 8 * g + 4 * h + i) * 64 + nt * 32 + ln] = f2bf(d[4 * g + i]);
        } else {
            #pragma unroll
            for (int g = 0; g < 4; g++) {
                ushort4 pv;
                pv.x = f2bf(d[4 * g + 0]); pv.y = f2bf(d[4 * g + 1]);
                pv.z = f2bf(d[4 * g + 2]); pv.w = f2bf(d[4 * g + 3]);
                *(ushort4*)&Wvit[(nt * 32 + ln) * 72 + mt * 32 + 8 * g + 4 * h] = pv;
            }
        }
    }
    // bq', bvi (lead wave); U1 = Wm·Wci (wave 1)
    if (tid < 64) {
        float s = bq[o];
        for (int t = 0; t < 64; t++) s += Wq_s[o * 68 + t] * bi_s[t];
        ws[o] = s * QS;
        float sv = bv[o];
        for (int t = 0; t < 64; t++) sv += Wv_s[o * 68 + t] * bi_s[t];
        bvi_s[o] = sv;
    } else if (tid < 96) {
        int a = (tid - 64) >> 3, c = (tid - 64) & 7;
        float s = 0.f;
        for (int t = 0; t < 64; t++) s += Wm_s[a * 64 + t] * Wci_s[t * 8 + c];
        U1[a * 8 + c] = s;
    }
    __syncthreads();
    if (tid < 64) {
        for (int a = 0; a < 4; a++) {
            float s = 0.f;
            for (int cc = 0; cc < 8; cc++) s += U1[a * 8 + cc] * Wc_s[cc * 64 + o];
            U2[a * 64 + o] = s;
        }
        float s = bci[o];
        for (int j = 0; j < 8; j++) s += Wci_s[o * 8 + j] * bc[j];
        c1[o] = s;
    }
    __syncthreads();
    {   // M = Wmi·U2
        const int i0 = (tid >> 6) * 16;
        #pragma unroll
        for (int ii = 0; ii < 16; ii++) {
            float s = 0.f;
            for (int a = 0; a < 4; a++) s += Wmi_s[o * 4 + a] * U2[a * 64 + i0 + ii];
            M_s[o * 68 + i0 + ii] = s;
        }
    }
    if (tid < 4) {
        float s = bm[tid];
        for (int i = 0; i < 64; i++) s += Wm_s[tid * 64 + i] * c1[i];
        c2[tid] = s;
    }
    __syncthreads();
    {   // Av = M·Wvi via MFMA (B-frags straight from transposed Wvit)
        f32x16 d = z16();
        #pragma unroll
        for (int c = 0; c < 4; c++) {
            const float* ap = M_s + (mt * 32 + ln) * 68 + c * 16 + h * 8;
            float4 a0 = *(const float4*)ap;
            float4 a1 = *(const float4*)(ap + 4);
            union { bf16x8 v; unsigned int u[4]; } t;
            t.u[0] = pk2r(a0.x, a0.y); t.u[1] = pk2r(a0.z, a0.w);
            t.u[2] = pk2r(a1.x, a1.y); t.u[3] = pk2r(a1.z, a1.w);
            bf16x8 bfb = *(const bf16x8*)&Wvit[(nt * 32 + ln) * 72 + c * 16 + h * 8];
            d = MFMA32(t.v, bfb, d, 0, 0, 0);
        }
        #pragma unroll
        for (int g = 0; g < 4; g++)
            #pragma unroll
            for (int i = 0; i < 4; i++)
                wsu[8192 + (mt * 32 + 8 * g + 4 * h + i) * 64 + nt * 32 + ln] = f2bf(d[4 * g + i]);
    }
    if (tid < 64) {  // ecv = Wmi·c2 + bmi + M·bvi
        float bvv = 0.f;
        for (int t = 0; t < 64; t++) bvv += M_s[o * 68 + t] * bvi_s[t];
        float cvv = bmi[o];
        for (int a = 0; a < 4; a++) cvv += Wmi_s[o * 4 + a] * c2[a];
        ws[64 + o] = cvv + bvv;
    }
}

// ---------------- phase B: KV projection (2 key-tiles per block) ----------------
__device__ __forceinline__ void kv_phase(const float* __restrict__ x,
                                         float* __restrict__ ws, int bid) {
    const int tid = threadIdx.x;
    const int w = tid >> 6;
    const int lane = tid & 63;
    const int ln = lane & 31;
    const int h = lane >> 5;
    const int bh = bid >> 4;          // block (qi + 16*bh): bh shared, kt0 = 2*qi
    const int b = bh >> 4, hh = bh & 15;
    const int kt0 = (2 * bid) & 31;

    const unsigned short* wsu = (const unsigned short*)(ws + FOLD_F);
    unsigned short* Kg = (unsigned short*)(ws + FOLD_F) + KG_OFF + (size_t)bh * (2048 * 64);
    unsigned short* Vg = (unsigned short*)(ws + FOLD_F) + VG_OFF + (size_t)bh * (64 * 2048);

    const int krl = (w >> 1) * 32 + ln;
    const int dt32 = (w & 1) * 32;

    bf16x8 akf[4], avf[4];
    #pragma unroll
    for (int c = 0; c < 4; c++) {
        int row = dt32 + ln;
        int col = c * 16 + h * 8;
        akf[c] = *(const bf16x8*)(wsu + 4096 + row * 64 + col);
        avf[c] = *(const bf16x8*)(wsu + 8192 + row * 64 + col);
    }
    float kmax = 0.f;
    #pragma unroll
    for (int t = 0; t < 2; t++) {
        const int kt = kt0 + t;
        bf16x8 xf[4];
        const float* xr = x + ((size_t)(b * SEQ + kt * 64 + krl) * DM + hh * 64);
        #pragma unroll
        for (int c = 0; c < 4; c++) {
            const float* p = xr + c * 16 + h * 8;
            float4 f0 = *(const float4*)p;
            float4 f1 = *(const float4*)(p + 4);
            union { bf16x8 v; unsigned int u[4]; } tt;
            tt.u[0] = pk2t(f0.x, f0.y); tt.u[1] = pk2t(f0.z, f0.w);
            tt.u[2] = pk2t(f1.x, f1.y); tt.u[3] = pk2t(f1.z, f1.w);
            xf[c] = tt.v;
        }
        f32x16 kacc = z16(), vacc = z16();
        #pragma unroll
        for (int c = 0; c < 4; c++) kacc = MFMA32(akf[c], xf[c], kacc, 0, 0, 0);
        #pragma unroll
        for (int c = 0; c < 4; c++) vacc = MFMA32(xf[c], avf[c], vacc, 0, 0, 0);
        #pragma unroll
        for (int i = 0; i < 16; i++) kmax = fmaxf(kmax, fabsf(kacc[i]));
        #pragma unroll
        for (int g = 0; g < 4; g++) {
            uint2 pk_, pv_;
            pk_.x = pk2r(kacc[4 * g + 0], kacc[4 * g + 1]);
            pk_.y = pk2r(kacc[4 * g + 2], kacc[4 * g + 3]);
            *(uint2*)&Kg[(size_t)(kt * 64 + krl) * 64 + dt32 + 8 * g + 4 * h] = pk_;
            pv_.x = pk2r(vacc[4 * g + 0], vacc[4 * g + 1]);
            pv_.y = pk2r(vacc[4 * g + 2], vacc[4 * g + 3]);
            *(uint2*)&Vg[(size_t)(dt32 + ln) * 2048 + kt * 64 + (w >> 1) * 32 + 8 * g + 4 * h] = pv_;
        }
    }
    #pragma unroll
    for (int d = 1; d < 64; d <<= 1) kmax = fmaxf(kmax, __shfl_xor(kmax, d));
    if (lane == 0) atomicMax((int*)ws + 128, __float_as_int(kmax));
}

// ---------------- phase C: flash attention, bound-based softmax ----------------
__device__ __forceinline__ void attn_phase(const float* __restrict__ x,
                                           const float* __restrict__ wsf,
                                           float* __restrict__ out,
                                           int qi, int bh) {
    __shared__ __align__(16) unsigned short ps_s[128 * 72];  // Q pack then P (wave-local rows)
    __shared__ __align__(16) unsigned short ks_s[64 * 72];   // K [key][dout]
    __shared__ __align__(16) unsigned short vt_s[64 * 72];   // V^T [dout][key]
    __shared__ float ls_l[128];

    const int tid = threadIdx.x;
    const int w = tid >> 6;
    const int lane = tid & 63;
    const int ln = lane & 31;
    const int h = lane >> 5;
    const int b = bh >> 4;
    const int hh = bh & 15;
    const int qbase = qi * 128;

    const unsigned short* wsu = (const unsigned short*)(wsf + FOLD_F);
    const unsigned short* Kg = wsu + KG_OFF + (size_t)bh * (2048 * 64);
    const unsigned short* Vg = wsu + VG_OFF + (size_t)bh * (64 * 2048);

    const float maxk = __int_as_float(((const int*)wsf)[128]) * 1.02f;
    const float ec0 = wsf[64 + ln];
    const float ec1 = wsf[96 + ln];

    // ---- Q projection + row L1 norm (for the softmax bound) ----
    bf16x8 qf[4];
    float l1 = 0.f;
    {
        bf16x8 xq[4];
        const float* xrow = x + ((size_t)(b * SEQ + qbase + w * 32 + ln) * DM + hh * 64);
        #pragma unroll
        for (int c = 0; c < 4; c++) {
            const float* p = xrow + c * 16 + h * 8;
            float4 f0 = *(const float4*)p;
            float4 f1 = *(const float4*)(p + 4);
            union { bf16x8 v; unsigned int u[4]; } t;
            t.u[0] = pk2t(f0.x, f0.y); t.u[1] = pk2t(f0.z, f0.w);
            t.u[2] = pk2t(f1.x, f1.y); t.u[3] = pk2t(f1.z, f1.w);
            xq[c] = t.v;
        }
        #pragma unroll
        for (int m = 0; m < 2; m++) {
            f32x16 acc;
            #pragma unroll
            for (int g = 0; g < 4; g++) {
                float4 b4 = *(const float4*)&wsf[m * 32 + 8 * g + 4 * h];
                acc[4 * g + 0] = b4.x; acc[4 * g + 1] = b4.y;
                acc[4 * g + 2] = b4.z; acc[4 * g + 3] = b4.w;
            }
            #pragma unroll
            for (int c = 0; c < 4; c++) {
                bf16x8 aq = *(const bf16x8*)(wsu + (m * 32 + ln) * 64 + c * 16 + h * 8);
                acc = MFMA32(aq, xq[c], acc, 0, 0, 0);
            }
            #pragma unroll
            for (int i = 0; i < 16; i++) l1 += fabsf(acc[i]);
            #pragma unroll
            for (int g = 0; g < 4; g++) {
                uint2 pw;
                pw.x = pk2r(acc[4 * g + 0], acc[4 * g + 1]);
                pw.y = pk2r(acc[4 * g + 2], acc[4 * g + 3]);
                *(uint2*)&ps_s[(w * 32 + ln) * 72 + m * 32 + 8 * g + 4 * h] = pw;
            }
        }
        #pragma unroll
        for (int c = 0; c < 4; c++)
            qf[c] = *(const bf16x8*)&ps_s[(w * 32 + ln) * 72 + c * 16 + h * 8];
    }
    l1 += __shfl_xor(l1, 32);
    const float Mrow = l1 * maxk;  // >= any score of this q-row (log2 domain)

    f32x16 o0 = z16(), o1 = z16();
    float l_i = 0.f;

    const int srow = tid >> 3;
    const int scol = (tid & 7) * 8;

    u16x8 ka, kb, va, vb;
    ka = *(const u16x8*)(Kg + (size_t)srow * 64 + scol);
    kb = *(const u16x8*)(Kg + (size_t)(srow + 32) * 64 + scol);
    va = *(const u16x8*)(Vg + (size_t)srow * 2048 + scol);
    vb = *(const u16x8*)(Vg + (size_t)(srow + 32) * 2048 + scol);
    *(u16x8*)&ks_s[srow * 72 + scol] = ka;
    *(u16x8*)&ks_s[(srow + 32) * 72 + scol] = kb;
    *(u16x8*)&vt_s[srow * 72 + scol] = va;
    *(u16x8*)&vt_s[(srow + 32) * 72 + scol] = vb;
    __syncthreads();

    for (int kt = 0; kt < SEQ / 64; kt++) {
        const bool more = (kt < SEQ / 64 - 1);
        if (more) {
            const int kn = (kt + 1) * 64;
            ka = *(const u16x8*)(Kg + (size_t)(kn + srow) * 64 + scol);
            kb = *(const u16x8*)(Kg + (size_t)(kn + srow + 32) * 64 + scol);
            va = *(const u16x8*)(Vg + (size_t)srow * 2048 + kn + scol);
            vb = *(const u16x8*)(Vg + (size_t)(srow + 32) * 2048 + kn + scol);
        }
        // S^T = K·Q^T (log2 domain)
        f32x16 st0 = z16(), st1 = z16();
        #pragma unroll
        for (int c = 0; c < 4; c++) {
            bf16x8 k0 = *(const bf16x8*)&ks_s[ln * 72 + c * 16 + h * 8];
            bf16x8 k1 = *(const bf16x8*)&ks_s[(32 + ln) * 72 + c * 16 + h * 8];
            st0 = MFMA32(k0, qf[c], st0, 0, 0, 0);
            st1 = MFMA32(k1, qf[c], st1, 0, 0, 0);
        }
        // P = exp2(s - Mrow); l summed from truncated P (self-consistent)
        float ss = 0.f;
        #pragma unroll
        for (int i = 0; i < 16; i++) {
            float e = EXP2(st0[i] - Mrow);
            st0[i] = __uint_as_float(__float_as_uint(e) & 0xffff0000u);
            ss += st0[i];
        }
        #pragma unroll
        for (int i = 0; i < 16; i++) {
            float e = EXP2(st1[i] - Mrow);
            st1[i] = __uint_as_float(__float_as_uint(e) & 0xffff0000u);
            ss += st1[i];
        }
        ss += __shfl_xor(ss, 32);
        l_i += ss;
        #pragma unroll
        for (int g = 0; g < 4; g++) {
            uint2 p0, p1;
            p0.x = pk2t(st0[4 * g + 0], st0[4 * g + 1]);
            p0.y = pk2t(st0[4 * g + 2], st0[4 * g + 3]);
            *(uint2*)&ps_s[(w * 32 + ln) * 72 + 8 * g + 4 * h] = p0;
            p1.x = pk2t(st1[4 * g + 0], st1[4 * g + 1]);
            p1.y = pk2t(st1[4 * g + 2], st1[4 * g + 3]);
            *(uint2*)&ps_s[(w * 32 + ln) * 72 + 32 + 8 * g + 4 * h] = p1;
        }
        // O += P·V
        #pragma unroll
        for (int c = 0; c < 4; c++) {
            bf16x8 pf = *(const bf16x8*)&ps_s[(w * 32 + ln) * 72 + c * 16 + h * 8];
            bf16x8 v0 = *(const bf16x8*)&vt_s[ln * 72 + c * 16 + h * 8];
            bf16x8 v1 = *(const bf16x8*)&vt_s[(32 + ln) * 72 + c * 16 + h * 8];
            o0 = MFMA32(pf, v0, o0, 0, 0, 0);
            o1 = MFMA32(pf, v1, o1, 0, 0, 0);
        }
        __syncthreads();  // reads of ks/vt done
        if (more) {
            *(u16x8*)&ks_s[srow * 72 + scol] = ka;
            *(u16x8*)&ks_s[(srow + 32) * 72 + scol] = kb;
            *(u16x8*)&vt_s[srow * 72 + scol] = va;
            *(u16x8*)&vt_s[(srow + 32) * 72 + scol] = vb;
        }
        __syncthreads();  // next tile visible
    }

    if (lane < 32) ls_l[w * 32 + lane] = l_i;
    #pragma unroll
    for (int g = 0; g < 4; g++) {
        float4 l4 = *(const float4*)&ls_l[w * 32 + 8 * g + 4 * h];
        float4 iv = make_float4(1.f / l4.x, 1.f / l4.y, 1.f / l4.z, 1.f / l4.w);
        #pragma unroll
        for (int i = 0; i < 4; i++) {
            float ivv = (i == 0) ? iv.x : (i == 1) ? iv.y : (i == 2) ? iv.z : iv.w;
            int q = qbase + w * 32 + 8 * g + 4 * h + i;
            float* orow = out + ((size_t)(b * SEQ + q) * DM + hh * 64);
            orow[ln] = o0[4 * g + i] * ivv + ec0;
            orow[32 + ln] = o1[4 * g + i] * ivv + ec1;
        }
    }
}

// ---------------- merged cooperative kernel ----------------
__global__ __launch_bounds__(256, 4)
void qmt_merged(const float* __restrict__ x, float* __restrict__ ws,
                float* __restrict__ out) {
    kv_phase(x, ws, blockIdx.x + 16 * blockIdx.y);
    __threadfence();
    cg::this_grid().sync();
    attn_phase(x, ws, out, blockIdx.x, blockIdx.y);
}

// ---------------- fallback: split launches ----------------
__global__ __launch_bounds__(256, 4)
void qmt_kv_only(const float* __restrict__ x, float* __restrict__ ws) {
    kv_phase(x, ws, blockIdx.x + 16 * blockIdx.y);
}
__global__ __launch_bounds__(256, 4)
void qmt_attn_only(const float* __restrict__ x, const float* __restrict__ ws,
                   float* __restrict__ out) {
    attn_phase(x, ws, out, blockIdx.x, blockIdx.y);
}

extern "C" void kernel_launch(void* const* d_in, const int* in_sizes, int n_in,
                              void* d_out, int out_size, void* d_ws, size_t ws_size,
                              hipStream_t stream) {
    const float* x = (const float*)d_in[0];
    float* wsf = (float*)d_ws;
    float* outp = (float*)d_out;

    qmt_fold<<<1, 256, 0, stream>>>(
        (const float*)d_in[1],  (const float*)d_in[2],
        (const float*)d_in[3],  (const float*)d_in[4],
        (const float*)d_in[5],  (const float*)d_in[6],
        (const float*)d_in[7],  (const float*)d_in[8],
        (const float*)d_in[9],  (const float*)d_in[10],
        (const float*)d_in[11], (const float*)d_in[12],
        (const float*)d_in[13], (const float*)d_in[14],
        (const float*)d_in[15], (const float*)d_in[16],
        wsf);

    dim3 grid(16, 64), blk(256);
    void* args[] = {(void*)&x, (void*)&wsf, (void*)&outp};
    hipError_t e = hipLaunchCooperativeKernel((const void*)qmt_merged, grid, blk,
                                              args, 0, stream);
    (void)hipGetLastError();  // clear sticky error if coop launch rejected
    if (e != hipSuccess) {
        qmt_kv_only<<<grid, blk, 0, stream>>>(x, wsf);
        qmt_attn_only<<<grid, blk, 0, stream>>>(x, wsf, outp);
    }
}

// Round 7
// 309.027 us; speedup vs baseline: 1.7023x; 1.7023x over previous
//
#include <hip/hip_runtime.h>

// QuantumMotivicTile — B=4, S=2048, H=16, hd=64, D=1024, fp32 I/O.
// final = softmax(q k^T / 8) @ v'' + ecv   (all weight algebra pre-folded)
//   Aq = QS·Wq·Wi (log2-domain scores, exp2 softmax), Ak = Wk·Wi,
//   Av = M·Wv·Wi, M = Wmi·Wm·Wci·Wc (rank 4), ecv = M·(Wv·bi+bv) + ecv.
// R7: split dispatches (coop grid.sync was a 270µs stall — reverted).
// Bound softmax: M_row = ||q'||1·max|k|·1.02 (no online max/rescale).
// σ-permuted storage columns so all MFMA-C stores are b128:
//   C-layout reg r=4g+i, lane-half h holds row 8g+4h+i; we store value (g,h,i)
//   of half kh at column 32h+16kh+4g+i. Applied consistently to {P cols, V cols}
//   (PV contraction) and {Q cols, K cols} (QK contraction) — bijection-safe.

#define SEQ 2048
#define DM  1024
#define QS  0.180336880111120429f  // 0.125 * log2(e)

typedef short bf16x8 __attribute__((ext_vector_type(8)));
typedef unsigned short u16x8 __attribute__((ext_vector_type(8)));
typedef float f32x16 __attribute__((ext_vector_type(16)));

#define MFMA32 __builtin_amdgcn_mfma_f32_32x32x16_bf16

#if defined(__has_builtin)
#if __has_builtin(__builtin_amdgcn_exp2f)
#define EXP2(x) __builtin_amdgcn_exp2f(x)
#endif
#endif
#ifndef EXP2
#define EXP2(x) exp2f(x)
#endif

// ws layout:
//   float [0..63] bq' (×QS), [64..127] ecv, [128] max|k| (int-compare atomicMax)
//   ushort wsu = (ushort*)(ws + 144):
//     [0..4095] Aq, [4096..8191] Ak, [8192..12287] Av   (row-major [dout][din])
//     [12288..) Kg[bh][key][σ2(dout)]; [+8388608..) Vtg[bh][dout][σ(key)]
#define FOLD_F 144
#define KG_OFF 12288
#define VG_OFF (12288 + 8388608)

__device__ __forceinline__ unsigned short f2bf(float f) {
    unsigned int v = __float_as_uint(f);
    unsigned int r = v + 0x7FFFu + ((v >> 16) & 1u);
    return (unsigned short)(r >> 16);
}
__device__ __forceinline__ unsigned int pk2r(float a, float b) {  // round
    return __builtin_amdgcn_perm(__float_as_uint(b) + 0x8000u,
                                 __float_as_uint(a) + 0x8000u, 0x07060302u);
}
__device__ __forceinline__ unsigned int pk2t(float a, float b) {  // truncate
    return __builtin_amdgcn_perm(__float_as_uint(b), __float_as_uint(a), 0x07060302u);
}
__device__ __forceinline__ f32x16 z16() {
    f32x16 v;
    #pragma unroll
    for (int i = 0; i < 16; i++) v[i] = 0.f;
    return v;
}
// pack C-accumulator regs [r0..r0+8) into one uint4 (bf16 round)
__device__ __forceinline__ uint4 pkC8(const f32x16& d, int r0) {
    uint4 u;
    u.x = pk2r(d[r0 + 0], d[r0 + 1]);
    u.y = pk2r(d[r0 + 2], d[r0 + 3]);
    u.z = pk2r(d[r0 + 4], d[r0 + 5]);
    u.w = pk2r(d[r0 + 6], d[r0 + 7]);
    return u;
}

// ---------------- weight folding (1 block, 256 thr, MFMA) ----------------
__global__ __launch_bounds__(256)
void qmt_fold(const float* __restrict__ Wi,  const float* __restrict__ bi,
              const float* __restrict__ Wq,  const float* __restrict__ bq,
              const float* __restrict__ Wk,  const float* __restrict__ bk,
              const float* __restrict__ Wv,  const float* __restrict__ bv,
              const float* __restrict__ Wc,  const float* __restrict__ bc,
              const float* __restrict__ Wci, const float* __restrict__ bci,
              const float* __restrict__ Wm,  const float* __restrict__ bm,
              const float* __restrict__ Wmi, const float* __restrict__ bmi,
              float* __restrict__ ws) {
    const int tid = threadIdx.x;
    const int o = tid & 63;
    const int w = tid >> 6;
    const int lane = tid & 63;
    const int ln = lane & 31;
    const int h = lane >> 5;

    __shared__ float Wi_s[64 * 68], Wq_s[64 * 68], Wk_s[64 * 68], Wv_s[64 * 68];
    __shared__ float M_s[64 * 68];
    __shared__ __align__(16) unsigned short Wvit[64 * 72];  // Wvi^T [din][dout] bf16
    __shared__ float Wc_s[512], Wci_s[512], Wm_s[256], Wmi_s[256];
    __shared__ float bi_s[64], bvi_s[64], c1[64], c2[4], U1[32], U2[256];

    unsigned short* wsu = (unsigned short*)(ws + FOLD_F);

    for (int i4 = tid; i4 < 1024; i4 += 256) {
        int r = i4 >> 4, c = (i4 & 15) * 4;
        *(float4*)&Wi_s[r * 68 + c] = *(const float4*)(Wi + i4 * 4);
        *(float4*)&Wq_s[r * 68 + c] = *(const float4*)(Wq + i4 * 4);
        *(float4*)&Wk_s[r * 68 + c] = *(const float4*)(Wk + i4 * 4);
        *(float4*)&Wv_s[r * 68 + c] = *(const float4*)(Wv + i4 * 4);
    }
    if (tid < 128) {
        *(float4*)&Wc_s[tid * 4]  = *(const float4*)(Wc + tid * 4);
        *(float4*)&Wci_s[tid * 4] = *(const float4*)(Wci + tid * 4);
    } else if (tid < 192) {
        int t = tid - 128;
        *(float4*)&Wm_s[t * 4]  = *(const float4*)(Wm + t * 4);
        *(float4*)&Wmi_s[t * 4] = *(const float4*)(Wmi + t * 4);
    }
    if (tid < 64) bi_s[tid] = bi[tid];
    if (tid == 0) ((int*)ws)[128] = 0;  // max|k| accumulator
    __syncthreads();

    const int mt = (w >> 1) & 1;  // output row tile
    const int nt = w & 1;         // output col tile
    bf16x8 wib[4];
    #pragma unroll
    for (int c = 0; c < 4; c++) {
        union { bf16x8 v; unsigned int u[4]; } t;
        #pragma unroll
        for (int j = 0; j < 4; j++) {
            float a = Wi_s[(c * 16 + h * 8 + 2 * j) * 68 + nt * 32 + ln];
            float b = Wi_s[(c * 16 + h * 8 + 2 * j + 1) * 68 + nt * 32 + ln];
            t.u[j] = pk2r(a, b);
        }
        wib[c] = t.v;
    }
    // products 0:Aq(×QS) 1:Ak 2:Wvi(→ transposed LDS)
    #pragma unroll
    for (int p = 0; p < 3; p++) {
        const float* src = (p == 0) ? Wq_s : (p == 1) ? Wk_s : Wv_s;
        f32x16 d = z16();
        #pragma unroll
        for (int c = 0; c < 4; c++) {
            const float* ap = src + (mt * 32 + ln) * 68 + c * 16 + h * 8;
            float4 a0 = *(const float4*)ap;
            float4 a1 = *(const float4*)(ap + 4);
            union { bf16x8 v; unsigned int u[4]; } t;
            t.u[0] = pk2r(a0.x, a0.y); t.u[1] = pk2r(a0.z, a0.w);
            t.u[2] = pk2r(a1.x, a1.y); t.u[3] = pk2r(a1.z, a1.w);
            d = MFMA32(t.v, wib[c], d, 0, 0, 0);
        }
        if (p == 0) {
            #pragma unroll
            for (int g = 0; g < 4; g++)
                #pragma unroll
                for (int i = 0; i < 4; i++)
                    wsu[(mt * 32 + 8 * g + 4 * h + i) * 64 + nt * 32 + ln] = f2bf(d[4 * g + i] * QS);
        } else if (p == 1) {
            #pragma unroll
            for (int g = 0; g < 4; g++)
                #pragma unroll
                for (int i = 0; i < 4; i++)
                    wsu[4096 + (mt * 32 + 8 * g + 4 * h + i) * 64 + nt * 32 + ln] = f2bf(d[4 * g + i]);
        } else {
            #pragma unroll
            for (int g = 0; g < 4; g++) {
                ushort4 pv;
                pv.x = f2bf(d[4 * g + 0]); pv.y = f2bf(d[4 * g + 1]);
                pv.z = f2bf(d[4 * g + 2]); pv.w = f2bf(d[4 * g + 3]);
                *(ushort4*)&Wvit[(nt * 32 + ln) * 72 + mt * 32 + 8 * g + 4 * h] = pv;
            }
        }
    }
    if (tid < 64) {
        float s = bq[o];
        for (int t = 0; t < 64; t++) s += Wq_s[o * 68 + t] * bi_s[t];
        ws[o] = s * QS;
        float sv = bv[o];
        for (int t = 0; t < 64; t++) sv += Wv_s[o * 68 + t] * bi_s[t];
        bvi_s[o] = sv;
    } else if (tid < 96) {
        int a = (tid - 64) >> 3, c = (tid - 64) & 7;
        float s = 0.f;
        for (int t = 0; t < 64; t++) s += Wm_s[a * 64 + t] * Wci_s[t * 8 + c];
        U1[a * 8 + c] = s;
    }
    __syncthreads();
    if (tid < 64) {
        for (int a = 0; a < 4; a++) {
            float s = 0.f;
            for (int cc = 0; cc < 8; cc++) s += U1[a * 8 + cc] * Wc_s[cc * 64 + o];
            U2[a * 64 + o] = s;
        }
        float s = bci[o];
        for (int j = 0; j < 8; j++) s += Wci_s[o * 8 + j] * bc[j];
        c1[o] = s;
    }
    __syncthreads();
    {   // M = Wmi·U2
        const int i0 = (tid >> 6) * 16;
        #pragma unroll
        for (int ii = 0; ii < 16; ii++) {
            float s = 0.f;
            for (int a = 0; a < 4; a++) s += Wmi_s[o * 4 + a] * U2[a * 64 + i0 + ii];
            M_s[o * 68 + i0 + ii] = s;
        }
    }
    if (tid < 4) {
        float s = bm[tid];
        for (int i = 0; i < 64; i++) s += Wm_s[tid * 64 + i] * c1[i];
        c2[tid] = s;
    }
    __syncthreads();
    {   // Av = M·Wvi via MFMA
        f32x16 d = z16();
        #pragma unroll
        for (int c = 0; c < 4; c++) {
            const float* ap = M_s + (mt * 32 + ln) * 68 + c * 16 + h * 8;
            float4 a0 = *(const float4*)ap;
            float4 a1 = *(const float4*)(ap + 4);
            union { bf16x8 v; unsigned int u[4]; } t;
            t.u[0] = pk2r(a0.x, a0.y); t.u[1] = pk2r(a0.z, a0.w);
            t.u[2] = pk2r(a1.x, a1.y); t.u[3] = pk2r(a1.z, a1.w);
            bf16x8 bfb = *(const bf16x8*)&Wvit[(nt * 32 + ln) * 72 + c * 16 + h * 8];
            d = MFMA32(t.v, bfb, d, 0, 0, 0);
        }
        #pragma unroll
        for (int g = 0; g < 4; g++)
            #pragma unroll
            for (int i = 0; i < 4; i++)
                wsu[8192 + (mt * 32 + 8 * g + 4 * h + i) * 64 + nt * 32 + ln] = f2bf(d[4 * g + i]);
    }
    if (tid < 64) {  // ecv = Wmi·c2 + bmi + M·bvi
        float bvv = 0.f;
        for (int t = 0; t < 64; t++) bvv += M_s[o * 68 + t] * bvi_s[t];
        float cvv = bmi[o];
        for (int a = 0; a < 4; a++) cvv += Wmi_s[o * 4 + a] * c2[a];
        ws[64 + o] = cvv + bvv;
    }
}

// ---------------- KV prepass: grid (32 ktiles, 64 bh) ----------------
__global__ __launch_bounds__(256)
void qmt_kv(const float* __restrict__ x, float* __restrict__ ws) {
    const int tid = threadIdx.x;
    const int w = tid >> 6;
    const int lane = tid & 63;
    const int ln = lane & 31;
    const int h = lane >> 5;
    const int kt = blockIdx.x;
    const int bh = blockIdx.y;
    const int b = bh >> 4, hh = bh & 15;

    const unsigned short* wsu = (const unsigned short*)(ws + FOLD_F);
    unsigned short* Kg = (unsigned short*)(ws + FOLD_F) + KG_OFF + (size_t)bh * (2048 * 64);
    unsigned short* Vg = (unsigned short*)(ws + FOLD_F) + VG_OFF + (size_t)bh * (64 * 2048);

    const int kh = w >> 1;          // key half (0..1)
    const int dt = w & 1;           // dout tile (0..1)
    const int krl = kh * 32 + ln;   // key row this lane produces/stages

    bf16x8 akf[4], avf[4];
    #pragma unroll
    for (int c = 0; c < 4; c++) {
        int row = dt * 32 + ln;
        int col = c * 16 + h * 8;
        akf[c] = *(const bf16x8*)(wsu + 4096 + row * 64 + col);
        avf[c] = *(const bf16x8*)(wsu + 8192 + row * 64 + col);
    }
    bf16x8 xf[4];
    const float* xr = x + ((size_t)(b * SEQ + kt * 64 + krl) * DM + hh * 64);
    #pragma unroll
    for (int c = 0; c < 4; c++) {
        const float* p = xr + c * 16 + h * 8;
        float4 f0 = *(const float4*)p;
        float4 f1 = *(const float4*)(p + 4);
        union { bf16x8 v; unsigned int u[4]; } tt;
        tt.u[0] = pk2t(f0.x, f0.y); tt.u[1] = pk2t(f0.z, f0.w);
        tt.u[2] = pk2t(f1.x, f1.y); tt.u[3] = pk2t(f1.z, f1.w);
        xf[c] = tt.v;
    }
    f32x16 kacc = z16(), vacc = z16();
    #pragma unroll
    for (int c = 0; c < 4; c++) kacc = MFMA32(akf[c], xf[c], kacc, 0, 0, 0);  // K^T
    #pragma unroll
    for (int c = 0; c < 4; c++) vacc = MFMA32(xf[c], avf[c], vacc, 0, 0, 0);  // V
    float kmax = 0.f;
    #pragma unroll
    for (int i = 0; i < 16; i++) kmax = fmaxf(kmax, fabsf(kacc[i]));
    // K: row = key (krl), σ2 dout cols 32h+16dt+0..15 — 2×b128
    {
        unsigned short* kp = Kg + (size_t)(kt * 64 + krl) * 64 + 32 * h + 16 * dt;
        *(uint4*)kp       = pkC8(kacc, 0);
        *((uint4*)kp + 1) = pkC8(kacc, 8);
    }
    // V: row = dout (dt*32+ln), σ key cols kt*64 + 32h+16kh+0..15 — 2×b128
    {
        unsigned short* vp = Vg + (size_t)(dt * 32 + ln) * 2048 + kt * 64 + 32 * h + 16 * kh;
        *(uint4*)vp       = pkC8(vacc, 0);
        *((uint4*)vp + 1) = pkC8(vacc, 8);
    }
    #pragma unroll
    for (int d = 1; d < 64; d <<= 1) kmax = fmaxf(kmax, __shfl_xor(kmax, d));
    if (lane == 0) atomicMax((int*)ws + 128, __float_as_int(kmax));
}

// ---------------- flash attention (bound softmax, σ-cols) ----------------
// grid (16 q-tiles, 64 bh), 256 thr = 4 waves; 4 blocks/CU.
__global__ __launch_bounds__(256, 4)
void qmt_attn(const float* __restrict__ x, const float* __restrict__ wsf,
              float* __restrict__ out) {
    __shared__ __align__(16) unsigned short ps_s[128 * 72];  // Q (prologue) then P; wave-local rows
    __shared__ __align__(16) unsigned short ks_s[64 * 72];   // K [key][σ2(dout)]
    __shared__ __align__(16) unsigned short vt_s[64 * 72];   // V^T [dout][σ(key)]
    __shared__ float ls_l[128];

    const int tid = threadIdx.x;
    const int w = tid >> 6;
    const int lane = tid & 63;
    const int ln = lane & 31;
    const int h = lane >> 5;
    const int b = blockIdx.y >> 4;
    const int hh = blockIdx.y & 15;
    const int qbase = blockIdx.x * 128;

    const unsigned short* wsu = (const unsigned short*)(wsf + FOLD_F);
    const unsigned short* Kg = wsu + KG_OFF + (size_t)blockIdx.y * (2048 * 64);
    const unsigned short* Vg = wsu + VG_OFF + (size_t)blockIdx.y * (64 * 2048);

    const float maxk = __int_as_float(((const int*)wsf)[128]) * 1.02f;
    const float ec0 = wsf[64 + ln];
    const float ec1 = wsf[96 + ln];

    // ---- Q projection + row L1 (softmax bound), σ2 col stores ----
    bf16x8 qf[4];
    float l1 = 0.f;
    {
        bf16x8 xq[4];
        const float* xrow = x + ((size_t)(b * SEQ + qbase + w * 32 + ln) * DM + hh * 64);
        #pragma unroll
        for (int c = 0; c < 4; c++) {
            const float* p = xrow + c * 16 + h * 8;
            float4 f0 = *(const float4*)p;
            float4 f1 = *(const float4*)(p + 4);
            union { bf16x8 v; unsigned int u[4]; } t;
            t.u[0] = pk2t(f0.x, f0.y); t.u[1] = pk2t(f0.z, f0.w);
            t.u[2] = pk2t(f1.x, f1.y); t.u[3] = pk2t(f1.z, f1.w);
            xq[c] = t.v;
        }
        #pragma unroll
        for (int m = 0; m < 2; m++) {
            f32x16 acc;
            #pragma unroll
            for (int g = 0; g < 4; g++) {
                float4 b4 = *(const float4*)&wsf[m * 32 + 8 * g + 4 * h];
                acc[4 * g + 0] = b4.x; acc[4 * g + 1] = b4.y;
                acc[4 * g + 2] = b4.z; acc[4 * g + 3] = b4.w;
            }
            #pragma unroll
            for (int c = 0; c < 4; c++) {
                bf16x8 aq = *(const bf16x8*)(wsu + (m * 32 + ln) * 64 + c * 16 + h * 8);
                acc = MFMA32(aq, xq[c], acc, 0, 0, 0);
            }
            #pragma unroll
            for (int i = 0; i < 16; i++) l1 += fabsf(acc[i]);
            unsigned short* qp = &ps_s[(w * 32 + ln) * 72 + 32 * h + 16 * m];
            *(uint4*)qp       = pkC8(acc, 0);
            *((uint4*)qp + 1) = pkC8(acc, 8);
        }
        #pragma unroll
        for (int c = 0; c < 4; c++)
            qf[c] = *(const bf16x8*)&ps_s[(w * 32 + ln) * 72 + c * 16 + h * 8];
    }
    l1 += __shfl_xor(l1, 32);
    const float Mrow = l1 * maxk;  // >= any score of this q-row (log2 domain)

    f32x16 o0 = z16(), o1 = z16();
    float l_i = 0.f;

    const int srow = tid >> 3;
    const int scol = (tid & 7) * 8;

    u16x8 ka, kb, va, vb;
    ka = *(const u16x8*)(Kg + (size_t)srow * 64 + scol);
    kb = *(const u16x8*)(Kg + (size_t)(srow + 32) * 64 + scol);
    va = *(const u16x8*)(Vg + (size_t)srow * 2048 + scol);
    vb = *(const u16x8*)(Vg + (size_t)(srow + 32) * 2048 + scol);
    *(u16x8*)&ks_s[srow * 72 + scol] = ka;
    *(u16x8*)&ks_s[(srow + 32) * 72 + scol] = kb;
    *(u16x8*)&vt_s[srow * 72 + scol] = va;
    *(u16x8*)&vt_s[(srow + 32) * 72 + scol] = vb;
    __syncthreads();

    for (int kt = 0; kt < SEQ / 64; kt++) {
        const bool more = (kt < SEQ / 64 - 1);
        if (more) {  // prefetch next tile into registers
            const int kn = (kt + 1) * 64;
            ka = *(const u16x8*)(Kg + (size_t)(kn + srow) * 64 + scol);
            kb = *(const u16x8*)(Kg + (size_t)(kn + srow + 32) * 64 + scol);
            va = *(const u16x8*)(Vg + (size_t)srow * 2048 + kn + scol);
            vb = *(const u16x8*)(Vg + (size_t)(srow + 32) * 2048 + kn + scol);
        }
        // S^T = K·Q^T (log2 domain)
        f32x16 st0 = z16(), st1 = z16();
        #pragma unroll
        for (int c = 0; c < 4; c++) {
            bf16x8 k0 = *(const bf16x8*)&ks_s[ln * 72 + c * 16 + h * 8];
            bf16x8 k1 = *(const bf16x8*)&ks_s[(32 + ln) * 72 + c * 16 + h * 8];
            st0 = MFMA32(k0, qf[c], st0, 0, 0, 0);
            st1 = MFMA32(k1, qf[c], st1, 0, 0, 0);
        }
        // P = exp2(s - Mrow); sum; σ col stores (2×b128 each half)
        float ss = 0.f;
        #pragma unroll
        for (int i = 0; i < 16; i++) { st0[i] = EXP2(st0[i] - Mrow); ss += st0[i]; }
        #pragma unroll
        for (int i = 0; i < 16; i++) { st1[i] = EXP2(st1[i] - Mrow); ss += st1[i]; }
        ss += __shfl_xor(ss, 32);
        l_i += ss;
        {
            unsigned short* pq = &ps_s[(w * 32 + ln) * 72 + 32 * h];
            uint4 u0, u1;
            u0.x = pk2t(st0[0], st0[1]);  u0.y = pk2t(st0[2], st0[3]);
            u0.z = pk2t(st0[4], st0[5]);  u0.w = pk2t(st0[6], st0[7]);
            u1.x = pk2t(st0[8], st0[9]);  u1.y = pk2t(st0[10], st0[11]);
            u1.z = pk2t(st0[12], st0[13]); u1.w = pk2t(st0[14], st0[15]);
            *(uint4*)pq = u0; *((uint4*)pq + 1) = u1;
            uint4 v0_, v1_;
            v0_.x = pk2t(st1[0], st1[1]);  v0_.y = pk2t(st1[2], st1[3]);
            v0_.z = pk2t(st1[4], st1[5]);  v0_.w = pk2t(st1[6], st1[7]);
            v1_.x = pk2t(st1[8], st1[9]);  v1_.y = pk2t(st1[10], st1[11]);
            v1_.z = pk2t(st1[12], st1[13]); v1_.w = pk2t(st1[14], st1[15]);
            *(uint4*)(pq + 16) = v0_; *((uint4*)(pq + 16) + 1) = v1_;
        }
        // O += P·V
        #pragma unroll
        for (int c = 0; c < 4; c++) {
            bf16x8 pf = *(const bf16x8*)&ps_s[(w * 32 + ln) * 72 + c * 16 + h * 8];
            bf16x8 v0 = *(const bf16x8*)&vt_s[ln * 72 + c * 16 + h * 8];
            bf16x8 v1 = *(const bf16x8*)&vt_s[(32 + ln) * 72 + c * 16 + h * 8];
            o0 = MFMA32(pf, v0, o0, 0, 0, 0);
            o1 = MFMA32(pf, v1, o1, 0, 0, 0);
        }
        __syncthreads();  // reads of ks/vt done
        if (more) {
            *(u16x8*)&ks_s[srow * 72 + scol] = ka;
            *(u16x8*)&ks_s[(srow + 32) * 72 + scol] = kb;
            *(u16x8*)&vt_s[srow * 72 + scol] = va;
            *(u16x8*)&vt_s[(srow + 32) * 72 + scol] = vb;
        }
        __syncthreads();  // next tile visible
    }

    if (lane < 32) ls_l[w * 32 + lane] = l_i;
    #pragma unroll
    for (int g = 0; g < 4; g++) {
        float4 l4 = *(const float4*)&ls_l[w * 32 + 8 * g + 4 * h];
        float4 iv = make_float4(1.f / l4.x, 1.f / l4.y, 1.f / l4.z, 1.f / l4.w);
        #pragma unroll
        for (int i = 0; i < 4; i++) {
            float ivv = (i == 0) ? iv.x : (i == 1) ? iv.y : (i == 2) ? iv.z : iv.w;
            int q = qbase + w * 32 + 8 * g + 4 * h + i;
            float* orow = out + ((size_t)(b * SEQ + q) * DM + hh * 64);
            orow[ln] = o0[4 * g + i] * ivv + ec0;
            orow[32 + ln] = o1[4 * g + i] * ivv + ec1;
        }
    }
}

extern "C" void kernel_launch(void* const* d_in, const int* in_sizes, int n_in,
                              void* d_out, int out_size, void* d_ws, size_t ws_size,
                              hipStream_t stream) {
    const float* x = (const float*)d_in[0];
    float* wsf = (float*)d_ws;

    qmt_fold<<<1, 256, 0, stream>>>(
        (const float*)d_in[1],  (const float*)d_in[2],
        (const float*)d_in[3],  (const float*)d_in[4],
        (const float*)d_in[5],  (const float*)d_in[6],
        (const float*)d_in[7],  (const float*)d_in[8],
        (const float*)d_in[9],  (const float*)d_in[10],
        (const float*)d_in[11], (const float*)d_in[12],
        (const float*)d_in[13], (const float*)d_in[14],
        (const float*)d_in[15], (const float*)d_in[16],
        wsf);

    dim3 gkv(SEQ / 64, 64);
    qmt_kv<<<gkv, 256, 0, stream>>>(x, wsf);
    dim3 grid(SEQ / 128, 64);
    qmt_attn<<<grid, 256, 0, stream>>>(x, wsf, (float*)d_out);
}